// Round 11
// baseline (305.058 us; speedup 1.0000x reference)
//
#include <hip/hip_runtime.h>

#define NPTS      10000
#define NPTS_PAD  10240          // 80 point-waves x 128 pts (2/lane)
#define NRAYS     4096
#define PGRP      20             // point groups (blocks of 4 waves = 512 pts)
#define RCHUNK    128            // ray chunks
#define RAYS_PC   32             // rays per chunk
#define PT_BLOCKS (NPTS_PAD / 256)   // 40 setup point-blocks
#define NFP       27             // float4 per lane (54 fields / 2)
#define LOG2E     1.44269504f

typedef float v2 __attribute__((ext_vector_type(2)));
typedef float v4 __attribute__((ext_vector_type(4)));

// ---- static device scratch ----
// g_T: transposed point data [g:80][fp:27][lane:64] v4
//   v4 = { f_{2fp}(p0), f_{2fp}(p1), f_{2fp+1}(p0), f_{2fp+1}(p1) }
//   fields: 0..2 = x,y,z; 3 = w1 (-delta*LOG2E); 4 = w0 (sigma*opacity);
//           5..52 = sh coeffs (k*3+ch order); 53 = pad
__device__ v4     g_T[80 * NFP * 64];
__device__ float  g_rays[(NRAYS + 2) * 24];  // o(3), d(3), sh*LOG2E(16), pad2
__device__ float  g_acc [NRAYS * 5];         // Sr,Sg,Sb,Sd,S
__device__ float  g_oppart[PT_BLOCKS];

__device__ __forceinline__ float fast_rcp(float x)  { return __builtin_amdgcn_rcpf(x); }
__device__ __forceinline__ float fast_exp2(float x) { return __builtin_amdgcn_exp2f(x); }
__device__ __forceinline__ float fast_sigmoid(float x) { return fast_rcp(1.0f + fast_exp2(-x * LOG2E)); }

__device__ __forceinline__ v2 v2splat(float s) { v2 r; r.x = s; r.y = s; return r; }
__device__ __forceinline__ v2 fmav(v2 a, v2 b, v2 c) { return __builtin_elementwise_fma(a, b, c); }
__device__ __forceinline__ v2 exp2v(v2 a) { v2 r; r.x = fast_exp2(a.x); r.y = fast_exp2(a.y); return r; }
__device__ __forceinline__ v2 rsqv(v2 a)  { v2 r; r.x = __builtin_amdgcn_rsqf(a.x); r.y = __builtin_amdgcn_rsqf(a.y); return r; }
__device__ __forceinline__ v2 rcpv(v2 a)  { v2 r; r.x = fast_rcp(a.x); r.y = fast_rcp(a.y); return r; }
__device__ __forceinline__ v2 f4lo(v4 f) { v2 r; r.x = f.x; r.y = f.y; return r; }
__device__ __forceinline__ v2 f4hi(v4 f) { v2 r; r.x = f.z; r.y = f.w; return r; }

// wave64 sum via DPP (VALU only, no DS pipe). Total lands in lane 63.
template <int CTRL>
__device__ __forceinline__ float dpp_step(float x) {
    return x + __int_as_float(
        __builtin_amdgcn_update_dpp(0, __float_as_int(x), CTRL, 0xf, 0xf, true));
}
__device__ __forceinline__ float wave_sum63(float x) {
    x = dpp_step<0x111>(x);  // row_shr:1
    x = dpp_step<0x112>(x);  // row_shr:2
    x = dpp_step<0x114>(x);  // row_shr:4
    x = dpp_step<0x118>(x);  // row_shr:8  -> lane15 of each row = row sum
    x = dpp_step<0x142>(x);  // row_bcast:15
    x = dpp_step<0x143>(x);  // row_bcast:31 -> lane63 = total
    return x;
}

// ---------------- Kernel 1: merged setup (rays + transposed points) ----------
__global__ __launch_bounds__(256) void setup(const float* __restrict__ ro,
                                             const float* __restrict__ rd,
                                             const float* __restrict__ pos,
                                             const int*   __restrict__ sidx,
                                             const float* __restrict__ log_delta,
                                             const float* __restrict__ log_sigma,
                                             const float* __restrict__ raw_op,
                                             const float* __restrict__ shc) {
    if (blockIdx.x < 16) {
        int r = blockIdx.x * 256 + threadIdx.x;
        float* a = g_acc + (size_t)r * 5;
        a[0] = a[1] = a[2] = a[3] = a[4] = 0.0f;

        float ox = ro[r * 3 + 0], oy = ro[r * 3 + 1], oz = ro[r * 3 + 2];
        float dx = rd[r * 3 + 0], dy = rd[r * 3 + 1], dz = rd[r * 3 + 2];
        float inv = __builtin_amdgcn_rsqf(dx * dx + dy * dy + dz * dz);
        float x = dx * inv, y = dy * inv, z = dz * inv;
        float* o = g_rays + (size_t)r * 24;
        o[0] = ox; o[1] = oy; o[2] = oz;
        o[3] = x;  o[4] = y;  o[5] = z;
        float* sh = o + 6;
        float zz = z * z, xx = x * x, yy = y * y;
        // SH basis prescaled by LOG2E so sigmoid uses exp2 directly
        sh[0]  = LOG2E * 0.282095f;
        sh[1]  = LOG2E * 0.488603f * y;
        sh[2]  = LOG2E * 0.488603f * z;
        sh[3]  = LOG2E * 0.488603f * x;
        sh[4]  = LOG2E * 1.092548f * x * y;
        sh[5]  = LOG2E * 1.092548f * y * z;
        sh[6]  = LOG2E * 0.315392f * (3.0f * zz - 1.0f);
        sh[7]  = LOG2E * 1.092548f * x * z;
        sh[8]  = LOG2E * 0.546274f * (xx - yy);
        sh[9]  = LOG2E * 0.590044f * y * (3.0f * xx - yy);
        sh[10] = LOG2E * 2.890611f * x * y * z;
        sh[11] = LOG2E * 0.457046f * y * (5.0f * zz - 1.0f);
        sh[12] = LOG2E * 0.373176f * z * (5.0f * zz - 3.0f);
        sh[13] = LOG2E * 0.457046f * x * (5.0f * zz - 1.0f);
        sh[14] = LOG2E * 1.445306f * z * (xx - yy);
        sh[15] = LOG2E * 0.590044f * x * (xx - 3.0f * yy);
    } else {
        int pb = blockIdx.x - 16;
        int n  = pb * 256 + threadIdx.x;        // [0, NPTS_PAD)
        int g  = n >> 7;                        // point-wave index
        int l  = (n >> 1) & 63;                 // lane owning this point
        int b  = n & 1;                         // slot within lane pair
        float vals[54];
        float op = 0.0f;
        if (n < NPTS) {
            vals[0] = pos[n * 3 + 0];
            vals[1] = pos[n * 3 + 1];
            vals[2] = pos[n * 3 + 2];
            int s = sidx[n];
            op = fast_sigmoid(raw_op[n]);
            vals[3] = -__expf(log_delta[s]) * LOG2E;
            vals[4] =  __expf(log_sigma[s]) * op;
            const float* src = shc + (size_t)n * 48;
#pragma unroll
            for (int i = 0; i < 48; ++i) vals[5 + i] = src[i];
        } else {
            vals[0] = 1e3f; vals[1] = 1e3f; vals[2] = 1e3f;
            vals[3] = 0.0f; vals[4] = 0.0f;     // w0=0 -> zero contribution
#pragma unroll
            for (int i = 0; i < 48; ++i) vals[5 + i] = 0.0f;
        }
        vals[53] = 0.0f;
        float* T = (float*)g_T;
#pragma unroll
        for (int f = 0; f < 54; ++f)
            T[(size_t)(((g * NFP + (f >> 1)) * 64 + l) * 4 + ((f & 1) << 1) + b)] = vals[f];

        __shared__ float blk;
        if (threadIdx.x == 0) blk = 0.0f;
        __syncthreads();
        float v = op;
#pragma unroll
        for (int off = 32; off > 0; off >>= 1) v += __shfl_down(v, off, 64);
        if ((threadIdx.x & 63) == 0) atomicAdd(&blk, v);
        __syncthreads();
        if (threadIdx.x == 0) g_oppart[pb] = blk;
    }
}

// ---------------- Kernel 2: main — point-resident lanes, rays iterate -------
// SH coeff i (0..47) lives at field 5+i:
#define CF(i) ((((5 + (i)) & 1)) ? f4hi(Q[(5 + (i)) >> 1]) : f4lo(Q[(5 + (i)) >> 1]))

__global__ __launch_bounds__(256, 3) void nerf_main() {
    int pb = blockIdx.x % PGRP;        // point group (4 waves = 512 points)
    int rc = blockIdx.x / PGRP;        // ray chunk
    int wv = threadIdx.x >> 6, lane = threadIdx.x & 63;
    int g  = pb * 4 + wv;              // global point-wave index [0,80)

    // ---- load this lane's 2 points (once): 27 coalesced dwordx4 ----
    v4 Q[NFP];
    {
        const v4* base = g_T + ((size_t)g * NFP * 64) + lane;
#pragma unroll
        for (int fp = 0; fp < NFP; ++fp) Q[fp] = base[fp * 64];
    }
    // PIN: claim each register modified so the compiler cannot re-load from
    // memory inside the loop (R10 failure: loads sunk into loop -> L2-bound).
#pragma unroll
    for (int fp = 0; fp < NFP; ++fp) asm volatile("" : "+v"(Q[fp]));

    v2 px = f4lo(Q[0]), py = f4hi(Q[0]);
    v2 pz = f4lo(Q[1]), w1 = f4hi(Q[1]);
    v2 w0 = f4lo(Q[2]);
    const v2 one2 = v2splat(1.0f);

    int r0 = rc * RAYS_PC;
    float A[22], B[22];

#define LOADRAY(dst, rr) {                                   \
        const float* rp_ = g_rays + (size_t)(rr) * 24;       \
        _Pragma("unroll")                                    \
        for (int i_ = 0; i_ < 22; ++i_) dst[i_] = rp_[i_]; }

#define BODY(R, ray) {                                                        \
        v2 rx = px - v2splat(R[0]);                                           \
        v2 ry = py - v2splat(R[1]);                                           \
        v2 rz = pz - v2splat(R[2]);                                           \
        v2 d2 = rx * rx; d2 = fmav(ry, ry, d2); d2 = fmav(rz, rz, d2);        \
        v2 inv = rsqv(d2);                                                    \
        v2 dn = rx * v2splat(R[3]);                                           \
        dn = fmav(ry, v2splat(R[4]), dn);                                     \
        dn = fmav(rz, v2splat(R[5]), dn);                                     \
        v2 t = fmav(-dn, inv, one2);                                          \
        v2 contrib = exp2v(w1 * t * t) * w0 * inv;                            \
        v2 sdist = d2 * inv * contrib;                                        \
        v2 s0 = v2splat(0.0f), s1 = s0, s2 = s0;                              \
        _Pragma("unroll")                                                     \
        for (int k = 0; k < 16; ++k) {                                        \
            v2 shk = v2splat(R[6 + k]);                                       \
            s0 = fmav(CF(3 * k + 0), shk, s0);                                \
            s1 = fmav(CF(3 * k + 1), shk, s1);                                \
            s2 = fmav(CF(3 * k + 2), shk, s2);                                \
        }                                                                     \
        v2 a0 = one2 + exp2v(-s0);                                            \
        v2 a1 = one2 + exp2v(-s1);                                            \
        v2 a2 = one2 + exp2v(-s2);                                            \
        v2 ab = a0 * a1;                                                      \
        v2 CI = contrib * rcpv(ab * a2);                                      \
        v2 vr = CI * (a1 * a2), vg = CI * (a0 * a2), vb = CI * ab;            \
        float hr = wave_sum63(vr.x + vr.y);                                   \
        float hg = wave_sum63(vg.x + vg.y);                                   \
        float hb = wave_sum63(vb.x + vb.y);                                   \
        float hd = wave_sum63(sdist.x + sdist.y);                             \
        float hs = wave_sum63(contrib.x + contrib.y);                         \
        if (lane == 63) {                                                     \
            float* ac = g_acc + (size_t)(ray) * 5;                            \
            atomicAdd(ac + 0, hr); atomicAdd(ac + 1, hg);                     \
            atomicAdd(ac + 2, hb); atomicAdd(ac + 3, hd);                     \
            atomicAdd(ac + 4, hs);                                            \
        }                                                                     \
    }

    LOADRAY(A, r0)
#pragma unroll 1
    for (int j = 0; j < RAYS_PC; j += 2) {
        LOADRAY(B, r0 + j + 1)
        BODY(A, r0 + j)
        LOADRAY(A, r0 + j + 2)          // last iter reads pad rays (harmless)
        BODY(B, r0 + j + 1)
    }
}

// ---------------- Kernel 3: finalize (f32 output) ----------------------------
__global__ void finalize(float* __restrict__ out) {
    int r = blockIdx.x * blockDim.x + threadIdx.x;
    if (r >= NRAYS) return;
    float opv = 0.0f;
#pragma unroll
    for (int i = 0; i < PT_BLOCKS; ++i) opv += g_oppart[i];
    const float* a = g_acc + (size_t)r * 5;
    float inv = fast_rcp(a[4] + 1e-8f);
    out[r * 3 + 0]     = a[0] * inv;
    out[r * 3 + 1]     = a[1] * inv;
    out[r * 3 + 2]     = a[2] * inv;
    out[NRAYS * 3 + r] = a[3] * inv;
    out[NRAYS * 4 + r] = opv * (1.0f / NPTS);
}

extern "C" void kernel_launch(void* const* d_in, const int* in_sizes, int n_in,
                              void* d_out, int out_size, void* d_ws, size_t ws_size,
                              hipStream_t stream) {
    const float* rays_o    = (const float*)d_in[0];
    const float* rays_d    = (const float*)d_in[1];
    const float* positions = (const float*)d_in[2];
    const int*   sidx      = (const int*)d_in[3];
    const float* log_delta = (const float*)d_in[4];
    const float* log_sigma = (const float*)d_in[5];
    const float* raw_op    = (const float*)d_in[6];
    const float* shc       = (const float*)d_in[7];

    setup<<<16 + PT_BLOCKS, 256, 0, stream>>>(
        rays_o, rays_d, positions, sidx, log_delta, log_sigma, raw_op, shc);
    nerf_main<<<PGRP * RCHUNK, 256, 0, stream>>>();
    finalize<<<NRAYS / 256, 256, 0, stream>>>((float*)d_out);
}

// Round 12
// 129.293 us; speedup vs baseline: 2.3594x; 2.3594x over previous
//
#include <hip/hip_runtime.h>
#include <hip/hip_bf16.h>

#define NPTS    10000
#define NRAYS   4096
#define PTILES  640              // 16 points per tile -> 10240 padded
#define RTILES  256              // 16 rays per tile
#define RGROUPS 64               // 4 ray-tiles (4 waves) per block
#define PCHUNKS 16               // point-tile chunks
#define TPC     (PTILES / PCHUNKS)   // 40 tiles per chunk
#define ABLK    64               // setup blocks, A part (256 rt x 64 lanes)
#define BBLK    160              // setup blocks, B part (640 pt x 64 lanes)
#define LOG2E   1.44269504f

typedef float f4  __attribute__((ext_vector_type(4)));
typedef short s8v __attribute__((ext_vector_type(8)));   // 8 bf16 = 4 VGPRs

// ---- static device scratch ----
// g_A: per ray-tile, 4 distinct A fragments {geo-d2, geo-pd, sh, const}
// g_B: per point-tile, 7 B fragments {d2, pd, c0, c1, c2, w1, L0}
__device__ s8v   g_A[RTILES * 4 * 64];
__device__ s8v   g_B[PTILES * 7 * 64];
__device__ float g_acc[NRAYS * 5];     // Sr,Sg,Sb,Sd,S
__device__ float g_oppart[BBLK];

__device__ __forceinline__ float fast_rcp(float x)  { return __builtin_amdgcn_rcpf(x); }
__device__ __forceinline__ float fast_exp2(float x) { return __builtin_amdgcn_exp2f(x); }
__device__ __forceinline__ float fast_sigmoid(float x) { return fast_rcp(1.0f + fast_exp2(-x * LOG2E)); }

__device__ __forceinline__ unsigned short bf16r(float x) {
    __hip_bfloat16 h = __float2bfloat16(x);
    return *reinterpret_cast<unsigned short*>(&h);
}
__device__ __forceinline__ float bf16f(unsigned short u) {
    return __uint_as_float((unsigned)u << 16);
}
__device__ __forceinline__ float bfhi(float x) { return bf16f(bf16r(x)); }

__device__ __forceinline__ s8v pk8(float a, float b, float c, float d,
                                   float e, float f, float g, float h) {
    s8v r;
    r[0] = (short)bf16r(a); r[1] = (short)bf16r(b);
    r[2] = (short)bf16r(c); r[3] = (short)bf16r(d);
    r[4] = (short)bf16r(e); r[5] = (short)bf16r(f);
    r[6] = (short)bf16r(g); r[7] = (short)bf16r(h);
    return r;
}

// DPP row-sum over each 16-lane row; lane (row*16+15) holds the row total.
template <int CTRL>
__device__ __forceinline__ float dpp_step(float x) {
    return x + __int_as_float(
        __builtin_amdgcn_update_dpp(0, __float_as_int(x), CTRL, 0xf, 0xf, true));
}
__device__ __forceinline__ float rowsum15(float x) {
    x = dpp_step<0x111>(x);  // row_shr:1
    x = dpp_step<0x112>(x);  // row_shr:2
    x = dpp_step<0x114>(x);  // row_shr:4
    x = dpp_step<0x118>(x);  // row_shr:8
    return x;
}

// ---------------- Kernel 1: setup (A frags, B frags, acc zero, opacity) ------
// k-slot maps (K=32, zero padded):
//  mfma0 d2 : A=[1,1,ooh,ool, oh(3), oh(3), ol(3)] B=[pph,ppl,1,1, -2ph(3), -2pl(3), -2ph(3)]
//  mfma1 pd : A=[dh(3), dh(3), dl(3), odh, odl]    B=[ph(3), pl(3), ph(3), -1, -1]
//  mfma2-4  : A=sh[k]*LOG2E (k<16)                 B=coeff_c[n][k]
//  mfma5 w1 : A=[1,1]                              B=[w1h, w1l]
//  mfma6 L0 : A=[1,1]                              B=[L0h, L0l]  (L0=log2(sigma*op))
__global__ __launch_bounds__(256) void setup(const float* __restrict__ ro,
                                             const float* __restrict__ rd,
                                             const float* __restrict__ pos,
                                             const int*   __restrict__ sidx,
                                             const float* __restrict__ log_delta,
                                             const float* __restrict__ log_sigma,
                                             const float* __restrict__ raw_op,
                                             const float* __restrict__ shc) {
    s8v zero8 = pk8(0, 0, 0, 0, 0, 0, 0, 0);
    if (blockIdx.x < ABLK) {
        int t = blockIdx.x * 256 + threadIdx.x;
        int rt = t >> 6, lane = t & 63, quad = lane >> 4;
        int r = rt * 16 + (lane & 15);
        if (quad == 0) {                       // zero accumulators (each ray once)
            float* a = g_acc + (size_t)r * 5;
            a[0] = a[1] = a[2] = a[3] = a[4] = 0.0f;
        }
        float ox = ro[r * 3 + 0], oy = ro[r * 3 + 1], oz = ro[r * 3 + 2];
        float rdx = rd[r * 3 + 0], rdy = rd[r * 3 + 1], rdz = rd[r * 3 + 2];
        float inv = __builtin_amdgcn_rsqf(rdx * rdx + rdy * rdy + rdz * rdz);
        float x = rdx * inv, y = rdy * inv, z = rdz * inv;
        float oo = ox * ox + oy * oy + oz * oz;
        float od = ox * x + oy * y + oz * z;
        float ohx = bfhi(ox), olx = ox - ohx;
        float ohy = bfhi(oy), oly = oy - ohy;
        float ohz = bfhi(oz), olz = oz - ohz;
        float dhx = bfhi(x),  dlx = x - dhx;
        float dhy = bfhi(y),  dly = y - dhy;
        float dhz = bfhi(z),  dlz = z - dhz;
        float ooh = bfhi(oo), ool = oo - ooh;
        float odh = bfhi(od), odl = od - odh;
        float zz = z * z, xx = x * x, yy = y * y;
        float sh[16];
        sh[0]  = LOG2E * 0.282095f;
        sh[1]  = LOG2E * 0.488603f * y;
        sh[2]  = LOG2E * 0.488603f * z;
        sh[3]  = LOG2E * 0.488603f * x;
        sh[4]  = LOG2E * 1.092548f * x * y;
        sh[5]  = LOG2E * 1.092548f * y * z;
        sh[6]  = LOG2E * 0.315392f * (3.0f * zz - 1.0f);
        sh[7]  = LOG2E * 1.092548f * x * z;
        sh[8]  = LOG2E * 0.546274f * (xx - yy);
        sh[9]  = LOG2E * 0.590044f * y * (3.0f * xx - yy);
        sh[10] = LOG2E * 2.890611f * x * y * z;
        sh[11] = LOG2E * 0.457046f * y * (5.0f * zz - 1.0f);
        sh[12] = LOG2E * 0.373176f * z * (5.0f * zz - 3.0f);
        sh[13] = LOG2E * 0.457046f * x * (5.0f * zz - 1.0f);
        sh[14] = LOG2E * 1.445306f * z * (xx - yy);
        sh[15] = LOG2E * 0.590044f * x * (xx - 3.0f * yy);

        s8v A0 = quad == 0 ? pk8(1, 1, ooh, ool, ohx, ohy, ohz, ohx)
               : quad == 1 ? pk8(ohy, ohz, olx, oly, olz, 0, 0, 0) : zero8;
        s8v A1 = quad == 0 ? pk8(dhx, dhy, dhz, dhx, dhy, dhz, dlx, dly)
               : quad == 1 ? pk8(dlz, odh, odl, 0, 0, 0, 0, 0) : zero8;
        s8v A2 = quad == 0 ? pk8(sh[0], sh[1], sh[2], sh[3], sh[4], sh[5], sh[6], sh[7])
               : quad == 1 ? pk8(sh[8], sh[9], sh[10], sh[11], sh[12], sh[13], sh[14], sh[15]) : zero8;
        s8v A3 = quad == 0 ? pk8(1, 1, 0, 0, 0, 0, 0, 0) : zero8;
        s8v* pa = g_A + (size_t)rt * 4 * 64 + lane;
        pa[0 * 64] = A0; pa[1 * 64] = A1; pa[2 * 64] = A2; pa[3 * 64] = A3;
    } else {
        int bb = blockIdx.x - ABLK;
        int t  = bb * 256 + threadIdx.x;
        int pt = t >> 6, lane = t & 63, quad = lane >> 4;
        int n  = pt * 16 + (lane & 15);
        float px, py, pz, w1, L0, op = 0.0f;
        float C0[16], C1[16], C2[16];
        if (n < NPTS) {
            px = pos[n * 3 + 0]; py = pos[n * 3 + 1]; pz = pos[n * 3 + 2];
            int s = sidx[n];
            op = fast_sigmoid(raw_op[n]);
            w1 = -__expf(log_delta[s]) * LOG2E;
            float w0 = __expf(log_sigma[s]) * op;
            L0 = __log2f(w0);
            const float* c = shc + (size_t)n * 48;
#pragma unroll
            for (int k = 0; k < 16; ++k) {
                C0[k] = c[k * 3 + 0]; C1[k] = c[k * 3 + 1]; C2[k] = c[k * 3 + 2];
            }
        } else {
            px = py = pz = 1e3f; w1 = 0.0f; L0 = -100.0f;   // contrib ~ 2^-100
#pragma unroll
            for (int k = 0; k < 16; ++k) { C0[k] = 0; C1[k] = 0; C2[k] = 0; }
        }
        float pp  = px * px + py * py + pz * pz;
        float phx = bfhi(px), plx = px - phx;
        float phy = bfhi(py), ply = py - phy;
        float phz = bfhi(pz), plz = pz - phz;
        float pph = bfhi(pp), ppl = pp - pph;
        float w1h = bfhi(w1), w1l = w1 - w1h;
        float L0h = bfhi(L0), L0l = L0 - L0h;

        s8v B0 = quad == 0 ? pk8(pph, ppl, 1, 1, -2 * phx, -2 * phy, -2 * phz, -2 * plx)
               : quad == 1 ? pk8(-2 * ply, -2 * plz, -2 * phx, -2 * phy, -2 * phz, 0, 0, 0) : zero8;
        s8v B1 = quad == 0 ? pk8(phx, phy, phz, plx, ply, plz, phx, phy)
               : quad == 1 ? pk8(phz, -1, -1, 0, 0, 0, 0, 0) : zero8;
        s8v B2 = quad == 0 ? pk8(C0[0], C0[1], C0[2], C0[3], C0[4], C0[5], C0[6], C0[7])
               : quad == 1 ? pk8(C0[8], C0[9], C0[10], C0[11], C0[12], C0[13], C0[14], C0[15]) : zero8;
        s8v B3 = quad == 0 ? pk8(C1[0], C1[1], C1[2], C1[3], C1[4], C1[5], C1[6], C1[7])
               : quad == 1 ? pk8(C1[8], C1[9], C1[10], C1[11], C1[12], C1[13], C1[14], C1[15]) : zero8;
        s8v B4 = quad == 0 ? pk8(C2[0], C2[1], C2[2], C2[3], C2[4], C2[5], C2[6], C2[7])
               : quad == 1 ? pk8(C2[8], C2[9], C2[10], C2[11], C2[12], C2[13], C2[14], C2[15]) : zero8;
        s8v B5 = quad == 0 ? pk8(w1h, w1l, 0, 0, 0, 0, 0, 0) : zero8;
        s8v B6 = quad == 0 ? pk8(L0h, L0l, 0, 0, 0, 0, 0, 0) : zero8;
        s8v* pb = g_B + (size_t)pt * 7 * 64 + lane;
        pb[0 * 64] = B0; pb[1 * 64] = B1; pb[2 * 64] = B2; pb[3 * 64] = B3;
        pb[4 * 64] = B4; pb[5 * 64] = B5; pb[6 * 64] = B6;

        // opacity mean: count each point exactly once (quad 0)
        __shared__ float blk;
        if (threadIdx.x == 0) blk = 0.0f;
        __syncthreads();
        float v = (quad == 0) ? op : 0.0f;
#pragma unroll
        for (int off = 32; off > 0; off >>= 1) v += __shfl_down(v, off, 64);
        if ((threadIdx.x & 63) == 0) atomicAdd(&blk, v);
        __syncthreads();
        if (threadIdx.x == 0) g_oppart[bb] = blk;
    }
}

// ---------------- Kernel 2: main — MFMA pairwise dots + VALU nonlinearities --
__global__ __launch_bounds__(256, 3) void nerf_main() {
    int rg = blockIdx.x & (RGROUPS - 1);   // consecutive blocks share a chunk (L2)
    int pc = blockIdx.x / RGROUPS;
    int wv = threadIdx.x >> 6, lane = threadIdx.x & 63;
    int rt = rg * 4 + wv;

    const s8v* pa = g_A + (size_t)rt * 4 * 64 + lane;
    s8v a0 = pa[0 * 64], a1 = pa[1 * 64], a2 = pa[2 * 64], a3 = pa[3 * 64];
    f4 z = {0.0f, 0.0f, 0.0f, 0.0f};

    float acc[5][4];
#pragma unroll
    for (int v = 0; v < 5; ++v)
#pragma unroll
        for (int i = 0; i < 4; ++i) acc[v][i] = 0.0f;

    const s8v* pb = g_B + (size_t)(pc * TPC) * 7 * 64 + lane;
#pragma unroll 1
    for (int ti = 0; ti < TPC; ++ti, pb += 7 * 64) {
        s8v b0 = pb[0 * 64], b1 = pb[1 * 64], b2 = pb[2 * 64], b3 = pb[3 * 64];
        s8v b4 = pb[4 * 64], b5 = pb[5 * 64], b6 = pb[6 * 64];
        f4 c0 = __builtin_amdgcn_mfma_f32_16x16x32_bf16(a0, b0, z, 0, 0, 0);  // d2
        f4 c1 = __builtin_amdgcn_mfma_f32_16x16x32_bf16(a1, b1, z, 0, 0, 0);  // pd
        f4 c2 = __builtin_amdgcn_mfma_f32_16x16x32_bf16(a2, b2, z, 0, 0, 0);  // s0*log2e
        f4 c3 = __builtin_amdgcn_mfma_f32_16x16x32_bf16(a2, b3, z, 0, 0, 0);  // s1*log2e
        f4 c4 = __builtin_amdgcn_mfma_f32_16x16x32_bf16(a2, b4, z, 0, 0, 0);  // s2*log2e
        f4 c5 = __builtin_amdgcn_mfma_f32_16x16x32_bf16(a3, b5, z, 0, 0, 0);  // w1
        f4 c6 = __builtin_amdgcn_mfma_f32_16x16x32_bf16(a3, b6, z, 0, 0, 0);  // L0
#pragma unroll
        for (int i = 0; i < 4; ++i) {
            float d2  = c0[i], pd = c1[i];
            float inv = __builtin_amdgcn_rsqf(d2);
            float t   = 1.0f - pd * inv;
            float arg = fmaf(c5[i] * t, t, c6[i]);      // w1*t^2 + log2(w0)
            float contrib = fast_exp2(arg) * inv;
            float dist = d2 * inv;
            float e0 = 1.0f + fast_exp2(-c2[i]);
            float e1 = 1.0f + fast_exp2(-c3[i]);
            float e2 = 1.0f + fast_exp2(-c4[i]);
            float P  = e0 * e1, Pa = P * e2;
            float CI = contrib * fast_rcp(Pa);
            acc[0][i] = fmaf(CI, e1 * e2, acc[0][i]);
            acc[1][i] = fmaf(CI, e0 * e2, acc[1][i]);
            acc[2][i] = fmaf(CI, P, acc[2][i]);
            acc[3][i] = fmaf(dist, contrib, acc[3][i]);
            acc[4][i] += contrib;
        }
    }

    // reduce over the 16 points (lanes of each row); lane row*16+15 holds totals
#pragma unroll
    for (int v = 0; v < 5; ++v)
#pragma unroll
        for (int i = 0; i < 4; ++i) acc[v][i] = rowsum15(acc[v][i]);
    if ((lane & 15) == 15) {
        int quad = lane >> 4;
#pragma unroll
        for (int i = 0; i < 4; ++i) {
            float* ac = g_acc + (size_t)(rt * 16 + quad * 4 + i) * 5;
            atomicAdd(ac + 0, acc[0][i]);
            atomicAdd(ac + 1, acc[1][i]);
            atomicAdd(ac + 2, acc[2][i]);
            atomicAdd(ac + 3, acc[3][i]);
            atomicAdd(ac + 4, acc[4][i]);
        }
    }
}

// ---------------- Kernel 3: finalize (f32 output) ----------------------------
__global__ void finalize(float* __restrict__ out) {
    int r = blockIdx.x * blockDim.x + threadIdx.x;
    if (r >= NRAYS) return;
    float opv = 0.0f;
    for (int i = 0; i < BBLK; ++i) opv += g_oppart[i];
    const float* a = g_acc + (size_t)r * 5;
    float inv = fast_rcp(a[4] + 1e-8f);
    out[r * 3 + 0]     = a[0] * inv;
    out[r * 3 + 1]     = a[1] * inv;
    out[r * 3 + 2]     = a[2] * inv;
    out[NRAYS * 3 + r] = a[3] * inv;
    out[NRAYS * 4 + r] = opv * (1.0f / NPTS);
}

extern "C" void kernel_launch(void* const* d_in, const int* in_sizes, int n_in,
                              void* d_out, int out_size, void* d_ws, size_t ws_size,
                              hipStream_t stream) {
    const float* rays_o    = (const float*)d_in[0];
    const float* rays_d    = (const float*)d_in[1];
    const float* positions = (const float*)d_in[2];
    const int*   sidx      = (const int*)d_in[3];
    const float* log_delta = (const float*)d_in[4];
    const float* log_sigma = (const float*)d_in[5];
    const float* raw_op    = (const float*)d_in[6];
    const float* shc       = (const float*)d_in[7];

    setup<<<ABLK + BBLK, 256, 0, stream>>>(
        rays_o, rays_d, positions, sidx, log_delta, log_sigma, raw_op, shc);
    nerf_main<<<RGROUPS * PCHUNKS, 256, 0, stream>>>();
    finalize<<<NRAYS / 256, 256, 0, stream>>>((float*)d_out);
}